// Round 2
// baseline (668.795 us; speedup 1.0000x reference)
//
#include <hip/hip_runtime.h>
#include <stdint.h>

typedef __bf16 v8bf __attribute__((ext_vector_type(8)));
typedef float f32x4 __attribute__((ext_vector_type(4)));

__device__ __forceinline__ float b2f(unsigned short u) {
    unsigned int x = ((unsigned int)u) << 16;
    return __builtin_bit_cast(float, x);
}
__device__ __forceinline__ unsigned short f2b(float f) {
    unsigned int x = __builtin_bit_cast(unsigned int, f);
    unsigned int r = (x + 0x7fffu + ((x >> 16) & 1u)) >> 16;  // RNE
    return (unsigned short)r;
}

__device__ __forceinline__ void load_lds16(const void* g, void* l) {
    __builtin_amdgcn_global_load_lds(
        (__attribute__((address_space(1))) void*)(const void*)g,
        (__attribute__((address_space(3))) void*)l, 16, 0, 0);
}

// ---------------- weight conversion fp32 -> bf16 packed wbuf ----------------
// wbuf layout (bf16 elements):
//   Wl0:0  Wr0:16384  Wl1:32768  Wr1:49152  Wl2:65536  Wr2:81920  W1:98304
//   bl0:114688 bl1:114816 bl2:114944 b1:115072 W2:115200 b2:115456  (total 115458)
struct WSrc { const float* p[7]; const float* s[6]; };

__global__ void k_cvtw(WSrc w, unsigned short* __restrict__ wbuf) {
    int idx = blockIdx.x * 256 + threadIdx.x;
    if (idx >= 115458) return;
    float v;
    if (idx < 114688) {
        v = w.p[idx >> 14][idx & 16383];
    } else {
        int rem = idx - 114688;
        int t, j;
        if (rem < 512)      { t = rem >> 7; j = rem & 127; }
        else if (rem < 768) { t = 4; j = rem - 512; }
        else                { t = 5; j = rem - 768; }
        v = w.s[t][j];
    }
    wbuf[idx] = f2b(v);
}

// ---------------- CSR build ----------------
__global__ void k_count(const int* __restrict__ dst, int* __restrict__ cnt, int E) {
    int i = blockIdx.x * 256 + threadIdx.x;
    if (i < E) atomicAdd(&cnt[dst[i]], 1);
}

__global__ void k_bsum(const int* __restrict__ cnt, int* __restrict__ bsum, int n) {
    __shared__ int s[256];
    int i = blockIdx.x * 256 + threadIdx.x;
    s[threadIdx.x] = (i < n) ? cnt[i] : 0;
    __syncthreads();
    for (int o = 128; o > 0; o >>= 1) {
        if (threadIdx.x < o) s[threadIdx.x] += s[threadIdx.x + o];
        __syncthreads();
    }
    if (threadIdx.x == 0) bsum[blockIdx.x] = s[0];
}

__global__ void k_scanb(const int* __restrict__ bsum, int* __restrict__ boff, int nb) {
    __shared__ int s[512];
    int t = threadIdx.x;
    int v0 = (t < nb) ? bsum[t] : 0;
    s[t] = v0;
    __syncthreads();
    for (int o = 1; o < 512; o <<= 1) {
        int v = (t >= o) ? s[t - o] : 0;
        __syncthreads();
        s[t] += v;
        __syncthreads();
    }
    if (t < nb) boff[t] = s[t] - v0;  // exclusive
}

__global__ void k_scanf(const int* __restrict__ cnt, const int* __restrict__ boff,
                        int* __restrict__ rs, int* __restrict__ pos,
                        float* __restrict__ inv, int n) {
    __shared__ int s[256];
    int t = threadIdx.x;
    int i = blockIdx.x * 256 + t;
    int c = (i < n) ? cnt[i] : 0;
    s[t] = c;
    __syncthreads();
    for (int o = 1; o < 256; o <<= 1) {
        int v = (t >= o) ? s[t - o] : 0;
        __syncthreads();
        s[t] += v;
        __syncthreads();
    }
    int start = boff[blockIdx.x] + s[t] - c;
    if (i < n) {
        rs[i] = start;
        pos[i] = start;
        inv[i] = 1.0f / (float)max(c, 1);
        if (i == n - 1) rs[n] = start + c;
    }
}

__global__ void k_fill(const int* __restrict__ src, const int* __restrict__ dst,
                       int* __restrict__ pos, int* __restrict__ csr, int E) {
    int i = blockIdx.x * 256 + threadIdx.x;
    if (i < E) {
        int p = atomicAdd(&pos[dst[i]], 1);
        csr[p] = src[i];
    }
}

// x (fp32 N x 128) -> bf16 xcat right half (stride 256)
__global__ void k_copyx(const float* __restrict__ x, unsigned short* __restrict__ xcat, int n) {
    int i = blockIdx.x * 256 + threadIdx.x;  // one float4 = 4 elems per thread
    if (i < n * 32) {
        int row = i >> 5, c4 = (i & 31) * 4;
        float4 v = *(const float4*)&x[(size_t)row * 128 + c4];
        ushort4 o;
        o.x = f2b(v.x); o.y = f2b(v.y); o.z = f2b(v.z); o.w = f2b(v.w);
        *(ushort4*)&xcat[(size_t)row * 256 + 128 + c4] = o;
    }
}

// mean-aggregate: wave per dst row; read xcat right half, write left half (bf16, scaled)
__global__ __launch_bounds__(256) void k_agg(const unsigned short* __restrict__ xcat,
                                             const int* __restrict__ rs, const int* __restrict__ csr,
                                             const float* __restrict__ inv_cnt,
                                             unsigned short* __restrict__ outL, int n) {
    int wid = threadIdx.x >> 6, lane = threadIdx.x & 63;
    int d = blockIdx.x * 4 + wid;
    if (d >= n) return;
    int s = rs[d], e = rs[d + 1];
    float ax = 0.f, ay = 0.f;
    for (int base = s; base < e; base += 64) {
        int nIdx = min(64, e - base);
        int myidx = (base + lane < e) ? csr[base + lane] : 0;
        for (int b = 0; b < nIdx; b++) {
            int srow = __shfl(myidx, b, 64);
            unsigned int v = *(const unsigned int*)&xcat[(size_t)srow * 256 + 128 + lane * 2];
            ax += b2f((unsigned short)(v & 0xffff));
            ay += b2f((unsigned short)(v >> 16));
        }
    }
    float ic = inv_cnt[d];
    unsigned int o = ((unsigned int)f2b(ay * ic) << 16) | f2b(ax * ic);
    *(unsigned int*)&outL[(size_t)d * 256 + lane * 2] = o;
}

// C(nrows x 128) = A(nrows x K, lda, +aoff) @ W^T ; W row n holds k-major weights.
// k<128 from W0, k>=128 from W1. bias bf16[128]. Y bf16 nrows x 128.
__global__ __launch_bounds__(256) void k_gemm(const unsigned short* __restrict__ A, int lda, int aoff,
                                              const unsigned short* __restrict__ W0,
                                              const unsigned short* __restrict__ W1,
                                              const unsigned short* __restrict__ bias,
                                              unsigned short* __restrict__ Y, int nrows, int K) {
    __shared__ __align__(16) unsigned short As[128 * 32];
    __shared__ __align__(16) unsigned short Ws[128 * 32];
    int t = threadIdx.x;
    int wid = t >> 6, lane = t & 63;
    int wm = wid >> 1, wn = wid & 1;
    int quad = lane >> 4, l16 = lane & 15;
    int m0 = blockIdx.x * 128;
    int srow = t >> 2;         // 0..63
    int scol = (t & 3) * 8;    // 0,8,16,24

    f32x4 acc[4][4] = {};

    for (int kc = 0; kc < K; kc += 32) {
        for (int q = 0; q < 2; q++) {
            int r = q * 64 + srow;
            int gr = m0 + r;
            if (gr >= nrows) gr = nrows - 1;
            load_lds16(A + (size_t)gr * lda + aoff + kc + scol, &As[r * 32 + scol]);
        }
        const unsigned short* Wp = (kc < 128) ? W0 : W1;
        int wkc = (kc < 128) ? kc : kc - 128;
        for (int q = 0; q < 2; q++) {
            int r = q * 64 + srow;
            load_lds16(Wp + (size_t)r * 128 + wkc + scol, &Ws[r * 32 + scol]);
        }
        __syncthreads();
        v8bf af[4], bfv[4];
        for (int i = 0; i < 4; i++) {
            int row = wm * 64 + i * 16 + l16;
            af[i] = *(const v8bf*)&As[row * 32 + quad * 8];
        }
        for (int j = 0; j < 4; j++) {
            int row = wn * 64 + j * 16 + l16;
            bfv[j] = *(const v8bf*)&Ws[row * 32 + quad * 8];
        }
        for (int i = 0; i < 4; i++)
            for (int j = 0; j < 4; j++)
                acc[i][j] = __builtin_amdgcn_mfma_f32_16x16x32_bf16(af[i], bfv[j], acc[i][j], 0, 0, 0);
        __syncthreads();
    }

    for (int j = 0; j < 4; j++) {
        int nn = wn * 64 + j * 16 + l16;
        float bn = b2f(bias[nn]);
        for (int i = 0; i < 4; i++) {
            int mbase = m0 + wm * 64 + i * 16 + quad * 4;
            for (int r = 0; r < 4; r++) {
                int row = mbase + r;
                if (row < nrows) Y[(size_t)row * 128 + nn] = f2b(acc[i][j][r] + bn);
            }
        }
    }
}

// column sums / sumsq of Y (bf16 n x 128) -> sums[0:128]=sum, sums[128:256]=sumsq
__global__ __launch_bounds__(256) void k_stats(const unsigned short* __restrict__ Y,
                                               float* __restrict__ sums, int n) {
    int t = threadIdx.x;
    int f2 = (t & 63) * 2, rsub = t >> 6;
    float sx = 0, sy = 0, qx = 0, qy = 0;
    for (int r = blockIdx.x * 4 + rsub; r < n; r += gridDim.x * 4) {
        unsigned int v = *(const unsigned int*)&Y[(size_t)r * 128 + f2];
        float a = b2f((unsigned short)(v & 0xffff));
        float b = b2f((unsigned short)(v >> 16));
        sx += a; sy += b; qx += a * a; qy += b * b;
    }
    __shared__ float ls[1024];
    ls[t] = sx; ls[256 + t] = sy; ls[512 + t] = qx; ls[768 + t] = qy;
    __syncthreads();
    if (t < 64) {
        float s0 = 0, s1 = 0, q0 = 0, q1 = 0;
        for (int k = 0; k < 4; k++) {
            s0 += ls[t + k * 64]; s1 += ls[256 + t + k * 64];
            q0 += ls[512 + t + k * 64]; q1 += ls[768 + t + k * 64];
        }
        atomicAdd(&sums[t * 2], s0); atomicAdd(&sums[t * 2 + 1], s1);
        atomicAdd(&sums[128 + t * 2], q0); atomicAdd(&sums[128 + t * 2 + 1], q1);
    }
}

__global__ void k_bnfin(const float* __restrict__ sums, float* __restrict__ muinv, float invN) {
    int f = threadIdx.x;  // 128
    float mu = sums[f] * invN;
    float var = sums[128 + f] * invN - mu * mu;
    muinv[f] = mu;
    muinv[128 + f] = rsqrtf(var + 1e-5f);
}

// normalize + relu + pack bf16, write to out (stride ldo)
__global__ __launch_bounds__(256) void k_bnrelu(const unsigned short* __restrict__ Y,
                                                const float* __restrict__ muinv,
                                                unsigned short* __restrict__ out, int ldo, int n) {
    int i = blockIdx.x * 256 + threadIdx.x;  // per 2 elements
    if (i >= n * 64) return;
    int row = i >> 6, f2 = (i & 63) * 2;
    unsigned int v = *(const unsigned int*)&Y[(size_t)row * 128 + f2];
    float a = (b2f((unsigned short)(v & 0xffff)) - muinv[f2]) * muinv[128 + f2];
    float b = (b2f((unsigned short)(v >> 16)) - muinv[f2 + 1]) * muinv[128 + f2 + 1];
    a = fmaxf(a, 0.f);
    b = fmaxf(b, 0.f);
    *(unsigned int*)&out[(size_t)row * ldo + f2] = ((unsigned int)f2b(b) << 16) | f2b(a);
}

// out (n x 2, fp32) = x5 (bf16, stride 256) @ W2^T + b2  ; wave per row
__global__ __launch_bounds__(256) void k_final(const unsigned short* __restrict__ x5,
                                               const unsigned short* __restrict__ W2,
                                               const unsigned short* __restrict__ b2v,
                                               float* __restrict__ out, int n) {
    int wid = threadIdx.x >> 6, lane = threadIdx.x & 63;
    int r = blockIdx.x * 4 + wid;
    if (r >= n) return;
    unsigned int v = *(const unsigned int*)&x5[(size_t)r * 256 + lane * 2];
    float a = b2f((unsigned short)(v & 0xffff));
    float b = b2f((unsigned short)(v >> 16));
    float d0 = a * b2f(W2[lane * 2]) + b * b2f(W2[lane * 2 + 1]);
    float d1 = a * b2f(W2[128 + lane * 2]) + b * b2f(W2[128 + lane * 2 + 1]);
    for (int o = 32; o > 0; o >>= 1) {
        d0 += __shfl_down(d0, o, 64);
        d1 += __shfl_down(d1, o, 64);
    }
    if (lane == 0) {
        float2 o2;
        o2.x = d0 + b2f(b2v[0]);
        o2.y = d1 + b2f(b2v[1]);
        *(float2*)&out[(size_t)r * 2] = o2;
    }
}

extern "C" void kernel_launch(void* const* d_in, const int* in_sizes, int n_in,
                              void* d_out, int out_size, void* d_ws, size_t ws_size,
                              hipStream_t stream) {
    const int N = in_sizes[0] / 128;
    const int E = in_sizes[1] / 2;

    const float* x = (const float*)d_in[0];
    const int* ei = (const int*)d_in[1];
    const int* srcp = ei;
    const int* dstp = ei + E;
    float* out = (float*)d_out;

    char* w = (char*)d_ws;
    auto align256 = [](size_t v) { return (v + 255) & ~(size_t)255; };
    size_t o_xcat = 0;
    size_t o_y    = align256(o_xcat + (size_t)N * 256 * 2);
    size_t o_csr  = align256(o_y + (size_t)N * 128 * 2);
    size_t o_rs   = align256(o_csr + (size_t)E * 4);
    size_t o_pos  = align256(o_rs + (size_t)(N + 1) * 4);
    size_t o_inv  = align256(o_pos + (size_t)N * 4);
    size_t o_cnt  = align256(o_inv + (size_t)N * 4);
    size_t o_stat = o_cnt + (size_t)N * 4;            // contiguous with cnt (one memset)
    size_t o_muinv= align256(o_stat + 4 * 256 * 4);
    size_t o_bsum = align256(o_muinv + 256 * 4);
    size_t o_boff = align256(o_bsum + 1024 * 4);
    size_t o_wbuf = align256(o_boff + 1024 * 4);

    unsigned short* xcat = (unsigned short*)(w + o_xcat);
    unsigned short* y    = (unsigned short*)(w + o_y);
    int* csr = (int*)(w + o_csr);
    int* rs  = (int*)(w + o_rs);
    int* pos = (int*)(w + o_pos);
    float* inv = (float*)(w + o_inv);
    int* cnt = (int*)(w + o_cnt);
    float* stat = (float*)(w + o_stat);
    float* muinv = (float*)(w + o_muinv);
    int* bsum = (int*)(w + o_bsum);
    int* boff = (int*)(w + o_boff);
    unsigned short* wbuf = (unsigned short*)(w + o_wbuf);

    // bf16 weight views inside wbuf
    const unsigned short* Wl[3] = {wbuf + 0,      wbuf + 32768, wbuf + 65536};
    const unsigned short* Wr[3] = {wbuf + 16384,  wbuf + 49152, wbuf + 81920};
    const unsigned short* W1b   = wbuf + 98304;
    const unsigned short* bl[3] = {wbuf + 114688, wbuf + 114816, wbuf + 114944};
    const unsigned short* b1b   = wbuf + 115072;
    const unsigned short* W2b   = wbuf + 115200;
    const unsigned short* b2b   = wbuf + 115456;

    WSrc wsrc;
    wsrc.p[0] = (const float*)d_in[2];   // Wl0
    wsrc.p[1] = (const float*)d_in[4];   // Wr0
    wsrc.p[2] = (const float*)d_in[5];   // Wl1
    wsrc.p[3] = (const float*)d_in[7];   // Wr1
    wsrc.p[4] = (const float*)d_in[8];   // Wl2
    wsrc.p[5] = (const float*)d_in[10];  // Wr2
    wsrc.p[6] = (const float*)d_in[11];  // W1
    wsrc.s[0] = (const float*)d_in[3];   // bl0
    wsrc.s[1] = (const float*)d_in[6];   // bl1
    wsrc.s[2] = (const float*)d_in[9];   // bl2
    wsrc.s[3] = (const float*)d_in[12];  // b1
    wsrc.s[4] = (const float*)d_in[13];  // W2
    wsrc.s[5] = (const float*)d_in[14];  // b2

    const int NB = (N + 255) / 256;

    // zero cnt + stats in one memset (they're contiguous)
    hipMemsetAsync(w + o_cnt, 0, (size_t)N * 4 + 4 * 256 * 4, stream);

    k_cvtw<<<(115458 + 255) / 256, 256, 0, stream>>>(wsrc, wbuf);
    k_count<<<(E + 255) / 256, 256, 0, stream>>>(dstp, cnt, E);
    k_bsum<<<NB, 256, 0, stream>>>(cnt, bsum, N);
    k_scanb<<<1, 512, 0, stream>>>(bsum, boff, NB);
    k_scanf<<<NB, 256, 0, stream>>>(cnt, boff, rs, pos, inv, N);
    k_fill<<<(E + 255) / 256, 256, 0, stream>>>(srcp, dstp, pos, csr, E);
    k_copyx<<<(N * 32 + 255) / 256, 256, 0, stream>>>(x, xcat, N);

    const int gemm_grid = (N + 127) / 128;
    const int agg_grid = (N + 3) / 4;
    const int bnr_grid = (N * 64 + 255) / 256;
    const float invN = 1.0f / (float)N;

    for (int i = 0; i < 3; i++) {
        k_agg<<<agg_grid, 256, 0, stream>>>(xcat, rs, csr, inv, xcat, N);
        k_gemm<<<gemm_grid, 256, 0, stream>>>(xcat, 256, 0, Wl[i], Wr[i], bl[i], y, N, 256);
        k_stats<<<512, 256, 0, stream>>>(y, stat + i * 256, N);
        k_bnfin<<<1, 128, 0, stream>>>(stat + i * 256, muinv, invN);
        k_bnrelu<<<bnr_grid, 256, 0, stream>>>(y, muinv, xcat + 128, 256, N);
    }
    // layer 4: x3 lives in xcat right half (lda=256, aoff=128), K=128
    k_gemm<<<gemm_grid, 256, 0, stream>>>(xcat, 256, 128, W1b, W1b, b1b, y, N, 128);
    k_stats<<<512, 256, 0, stream>>>(y, stat + 3 * 256, N);
    k_bnfin<<<1, 128, 0, stream>>>(stat + 3 * 256, muinv, invN);
    k_bnrelu<<<bnr_grid, 256, 0, stream>>>(y, muinv, xcat, 256, N);
    // final projection from xcat left half
    k_final<<<agg_grid, 256, 0, stream>>>(xcat, W2b, b2b, out, N);
}

// Round 3
// 464.483 us; speedup vs baseline: 1.4399x; 1.4399x over previous
//
#include <hip/hip_runtime.h>
#include <stdint.h>

typedef __bf16 v8bf __attribute__((ext_vector_type(8)));
typedef float f32x4 __attribute__((ext_vector_type(4)));

__device__ __forceinline__ float b2f(unsigned short u) {
    unsigned int x = ((unsigned int)u) << 16;
    return __builtin_bit_cast(float, x);
}
__device__ __forceinline__ float b2f_lo(unsigned int v) {
    return __builtin_bit_cast(float, v << 16);
}
__device__ __forceinline__ float b2f_hi(unsigned int v) {
    return __builtin_bit_cast(float, v & 0xffff0000u);
}
__device__ __forceinline__ unsigned short f2b(float f) {
    unsigned int x = __builtin_bit_cast(unsigned int, f);
    unsigned int r = (x + 0x7fffu + ((x >> 16) & 1u)) >> 16;  // RNE
    return (unsigned short)r;
}

__device__ __forceinline__ void load_lds16(const void* g, void* l) {
    __builtin_amdgcn_global_load_lds(
        (__attribute__((address_space(1))) void*)(const void*)g,
        (__attribute__((address_space(3))) void*)l, 16, 0, 0);
}

// ---------------- weight conversion fp32 -> bf16 packed wbuf ----------------
// wbuf layout (bf16 elements):
//   Wl0:0  Wr0:16384  Wl1:32768  Wr1:49152  Wl2:65536  Wr2:81920  W1:98304
//   bl0:114688 bl1:114816 bl2:114944 b1:115072 W2:115200 b2:115456  (total 115458)
struct WSrc { const float* p[7]; const float* s[6]; };

__global__ void k_cvtw(WSrc w, unsigned short* __restrict__ wbuf) {
    int idx = blockIdx.x * 256 + threadIdx.x;
    if (idx >= 115458) return;
    float v;
    if (idx < 114688) {
        v = w.p[idx >> 14][idx & 16383];
    } else {
        int rem = idx - 114688;
        int t, j;
        if (rem < 512)      { t = rem >> 7; j = rem & 127; }
        else if (rem < 768) { t = 4; j = rem - 512; }
        else                { t = 5; j = rem - 768; }
        v = w.s[t][j];
    }
    wbuf[idx] = f2b(v);
}

// ---------------- CSR build ----------------
__global__ void k_count(const int* __restrict__ dst, int* __restrict__ cnt, int E) {
    int i = blockIdx.x * 256 + threadIdx.x;
    if (i < E) atomicAdd(&cnt[dst[i]], 1);
}

__global__ void k_bsum(const int* __restrict__ cnt, int* __restrict__ bsum, int n) {
    __shared__ int s[256];
    int i = blockIdx.x * 256 + threadIdx.x;
    s[threadIdx.x] = (i < n) ? cnt[i] : 0;
    __syncthreads();
    for (int o = 128; o > 0; o >>= 1) {
        if (threadIdx.x < o) s[threadIdx.x] += s[threadIdx.x + o];
        __syncthreads();
    }
    if (threadIdx.x == 0) bsum[blockIdx.x] = s[0];
}

__global__ void k_scanb(const int* __restrict__ bsum, int* __restrict__ boff, int nb) {
    __shared__ int s[512];
    int t = threadIdx.x;
    int v0 = (t < nb) ? bsum[t] : 0;
    s[t] = v0;
    __syncthreads();
    for (int o = 1; o < 512; o <<= 1) {
        int v = (t >= o) ? s[t - o] : 0;
        __syncthreads();
        s[t] += v;
        __syncthreads();
    }
    if (t < nb) boff[t] = s[t] - v0;  // exclusive
}

__global__ void k_scanf(const int* __restrict__ cnt, const int* __restrict__ boff,
                        int* __restrict__ rs, int* __restrict__ pos,
                        float* __restrict__ inv, int n) {
    __shared__ int s[256];
    int t = threadIdx.x;
    int i = blockIdx.x * 256 + t;
    int c = (i < n) ? cnt[i] : 0;
    s[t] = c;
    __syncthreads();
    for (int o = 1; o < 256; o <<= 1) {
        int v = (t >= o) ? s[t - o] : 0;
        __syncthreads();
        s[t] += v;
        __syncthreads();
    }
    int start = boff[blockIdx.x] + s[t] - c;
    if (i < n) {
        rs[i] = start;
        pos[i] = start;
        inv[i] = 1.0f / (float)max(c, 1);
        if (i == n - 1) rs[n] = start + c;
    }
}

__global__ void k_fill(const int* __restrict__ src, const int* __restrict__ dst,
                       int* __restrict__ pos, int* __restrict__ csr, int E) {
    int i = blockIdx.x * 256 + threadIdx.x;
    if (i < E) {
        int p = atomicAdd(&pos[dst[i]], 1);
        csr[p] = src[i];
    }
}

// x (fp32 N x 128) -> bf16 xcat right half (stride 256)
__global__ void k_copyx(const float* __restrict__ x, unsigned short* __restrict__ xcat, int n) {
    int i = blockIdx.x * 256 + threadIdx.x;  // one float4 = 4 elems per thread
    if (i < n * 32) {
        int row = i >> 5, c4 = (i & 31) * 4;
        float4 v = *(const float4*)&x[(size_t)row * 128 + c4];
        ushort4 o;
        o.x = f2b(v.x); o.y = f2b(v.y); o.z = f2b(v.z); o.w = f2b(v.w);
        *(ushort4*)&xcat[(size_t)row * 256 + 128 + c4] = o;
    }
}

// mean-aggregate: wave per dst row; 8-way ILP over edges (predicated tail).
__global__ __launch_bounds__(256) void k_agg(const unsigned short* __restrict__ xcat,
                                             const int* __restrict__ rs, const int* __restrict__ csr,
                                             const float* __restrict__ inv_cnt,
                                             unsigned short* __restrict__ outL, int n) {
    int wid = threadIdx.x >> 6, lane = threadIdx.x & 63;
    int d = blockIdx.x * 4 + wid;
    if (d >= n) return;
    int s = rs[d], e = rs[d + 1];
    int deg = e - s;
    float ax = 0.f, ay = 0.f;
    for (int base = 0; base < deg; base += 64) {
        int cnt64 = min(64, deg - base);
        int myidx = (base + lane < deg) ? csr[s + base + lane] : 0;
        for (int b = 0; b < cnt64; b += 8) {
            int i0 = __shfl(myidx, b, 64);
            int i1 = __shfl(myidx, b + 1, 64);
            int i2 = __shfl(myidx, b + 2, 64);
            int i3 = __shfl(myidx, b + 3, 64);
            int i4 = __shfl(myidx, b + 4, 64);
            int i5 = __shfl(myidx, b + 5, 64);
            int i6 = __shfl(myidx, b + 6, 64);
            int i7 = __shfl(myidx, b + 7, 64);
            unsigned int v0 = *(const unsigned int*)&xcat[(size_t)i0 * 256 + 128 + lane * 2];
            unsigned int v1 = *(const unsigned int*)&xcat[(size_t)i1 * 256 + 128 + lane * 2];
            unsigned int v2 = *(const unsigned int*)&xcat[(size_t)i2 * 256 + 128 + lane * 2];
            unsigned int v3 = *(const unsigned int*)&xcat[(size_t)i3 * 256 + 128 + lane * 2];
            unsigned int v4 = *(const unsigned int*)&xcat[(size_t)i4 * 256 + 128 + lane * 2];
            unsigned int v5 = *(const unsigned int*)&xcat[(size_t)i5 * 256 + 128 + lane * 2];
            unsigned int v6 = *(const unsigned int*)&xcat[(size_t)i6 * 256 + 128 + lane * 2];
            unsigned int v7 = *(const unsigned int*)&xcat[(size_t)i7 * 256 + 128 + lane * 2];
            float w1 = (b + 1 < cnt64) ? 1.f : 0.f;
            float w2 = (b + 2 < cnt64) ? 1.f : 0.f;
            float w3 = (b + 3 < cnt64) ? 1.f : 0.f;
            float w4 = (b + 4 < cnt64) ? 1.f : 0.f;
            float w5 = (b + 5 < cnt64) ? 1.f : 0.f;
            float w6 = (b + 6 < cnt64) ? 1.f : 0.f;
            float w7 = (b + 7 < cnt64) ? 1.f : 0.f;
            ax += b2f_lo(v0);            ay += b2f_hi(v0);
            ax += w1 * b2f_lo(v1);       ay += w1 * b2f_hi(v1);
            ax += w2 * b2f_lo(v2);       ay += w2 * b2f_hi(v2);
            ax += w3 * b2f_lo(v3);       ay += w3 * b2f_hi(v3);
            ax += w4 * b2f_lo(v4);       ay += w4 * b2f_hi(v4);
            ax += w5 * b2f_lo(v5);       ay += w5 * b2f_hi(v5);
            ax += w6 * b2f_lo(v6);       ay += w6 * b2f_hi(v6);
            ax += w7 * b2f_lo(v7);       ay += w7 * b2f_hi(v7);
        }
    }
    float ic = inv_cnt[d];
    unsigned int o = ((unsigned int)f2b(ay * ic) << 16) | f2b(ax * ic);
    *(unsigned int*)&outL[(size_t)d * 256 + lane * 2] = o;
}

// C(nrows x 128) = A(nrows x K, lda, +aoff) @ W^T, fused column stats (32 slices).
__global__ __launch_bounds__(256) void k_gemm(const unsigned short* __restrict__ A, int lda, int aoff,
                                              const unsigned short* __restrict__ W0,
                                              const unsigned short* __restrict__ W1,
                                              const unsigned short* __restrict__ bias,
                                              unsigned short* __restrict__ Y,
                                              float* __restrict__ statp, int nrows, int K) {
    __shared__ __align__(16) unsigned short As[128 * 32];
    __shared__ __align__(16) unsigned short Ws[128 * 32];
    int t = threadIdx.x;
    int wid = t >> 6, lane = t & 63;
    int wm = wid >> 1, wn = wid & 1;
    int quad = lane >> 4, l16 = lane & 15;
    int m0 = blockIdx.x * 128;
    int srow = t >> 2;         // 0..63
    int scol = (t & 3) * 8;    // 0,8,16,24

    f32x4 acc[4][4] = {};

    for (int kc = 0; kc < K; kc += 32) {
        for (int q = 0; q < 2; q++) {
            int r = q * 64 + srow;
            int gr = m0 + r;
            if (gr >= nrows) gr = nrows - 1;
            load_lds16(A + (size_t)gr * lda + aoff + kc + scol, &As[r * 32 + scol]);
        }
        const unsigned short* Wp = (kc < 128) ? W0 : W1;
        int wkc = (kc < 128) ? kc : kc - 128;
        for (int q = 0; q < 2; q++) {
            int r = q * 64 + srow;
            load_lds16(Wp + (size_t)r * 128 + wkc + scol, &Ws[r * 32 + scol]);
        }
        __syncthreads();
        v8bf af[4], bfv[4];
        for (int i = 0; i < 4; i++) {
            int row = wm * 64 + i * 16 + l16;
            af[i] = *(const v8bf*)&As[row * 32 + quad * 8];
        }
        for (int j = 0; j < 4; j++) {
            int row = wn * 64 + j * 16 + l16;
            bfv[j] = *(const v8bf*)&Ws[row * 32 + quad * 8];
        }
        for (int i = 0; i < 4; i++)
            for (int j = 0; j < 4; j++)
                acc[i][j] = __builtin_amdgcn_mfma_f32_16x16x32_bf16(af[i], bfv[j], acc[i][j], 0, 0, 0);
        __syncthreads();
    }

    float* sp = statp + (blockIdx.x & 31) * 256;
    for (int j = 0; j < 4; j++) {
        int nn = wn * 64 + j * 16 + l16;
        float bn = b2f(bias[nn]);
        float cs = 0.f, cq = 0.f;
        for (int i = 0; i < 4; i++) {
            int mbase = m0 + wm * 64 + i * 16 + quad * 4;
            for (int r = 0; r < 4; r++) {
                int row = mbase + r;
                float v = acc[i][j][r] + bn;
                if (row < nrows) {
                    Y[(size_t)row * 128 + nn] = f2b(v);
                    cs += v;
                    cq += v * v;
                }
            }
        }
        cs += __shfl_xor(cs, 16, 64); cq += __shfl_xor(cq, 16, 64);
        cs += __shfl_xor(cs, 32, 64); cq += __shfl_xor(cq, 32, 64);
        if (lane < 16) {
            atomicAdd(&sp[nn], cs);
            atomicAdd(&sp[128 + nn], cq);
        }
    }
}

// BN(muinv from 32-slice stats) + ReLU + bf16 pack; uint4 (8 feats/thread)
__global__ __launch_bounds__(256) void k_bnrelu(const unsigned short* __restrict__ Y,
                                                const float* __restrict__ statp,
                                                unsigned short* __restrict__ out, int ldo,
                                                int n, float invN) {
    __shared__ float smu[128], sinv[128];
    int t = threadIdx.x;
    if (t < 128) {
        float s = 0.f, q = 0.f;
        for (int sl = 0; sl < 32; sl++) {
            s += statp[sl * 256 + t];
            q += statp[sl * 256 + 128 + t];
        }
        float mu = s * invN;
        float var = q * invN - mu * mu;
        smu[t] = mu;
        sinv[t] = rsqrtf(var + 1e-5f);
    }
    __syncthreads();
    int i = blockIdx.x * 256 + t;  // 8 feats per thread
    if (i >= n * 16) return;
    int row = i >> 4, f8 = (i & 15) * 8;
    uint4 v = *(const uint4*)&Y[(size_t)row * 128 + f8];
    unsigned int u[4] = {v.x, v.y, v.z, v.w};
    uint4 o;
    unsigned int* op = (unsigned int*)&o;
    for (int k = 0; k < 4; k++) {
        int f = f8 + k * 2;
        float a = fmaxf((b2f_lo(u[k]) - smu[f]) * sinv[f], 0.f);
        float b = fmaxf((b2f_hi(u[k]) - smu[f + 1]) * sinv[f + 1], 0.f);
        op[k] = ((unsigned int)f2b(b) << 16) | f2b(a);
    }
    *(uint4*)&out[(size_t)row * ldo + f8] = o;
}

// layer-4 BN + ReLU + final 128->2 projection fused; wave per row, fp32 out
__global__ __launch_bounds__(256) void k_bnfinal(const unsigned short* __restrict__ Y,
                                                 const float* __restrict__ statp,
                                                 const unsigned short* __restrict__ W2,
                                                 const unsigned short* __restrict__ b2v,
                                                 float* __restrict__ out, int n, float invN) {
    __shared__ float smu[128], sinv[128];
    int t = threadIdx.x;
    if (t < 128) {
        float s = 0.f, q = 0.f;
        for (int sl = 0; sl < 32; sl++) {
            s += statp[sl * 256 + t];
            q += statp[sl * 256 + 128 + t];
        }
        float mu = s * invN;
        float var = q * invN - mu * mu;
        smu[t] = mu;
        sinv[t] = rsqrtf(var + 1e-5f);
    }
    __syncthreads();
    int wid = t >> 6, lane = t & 63;
    int r = blockIdx.x * 4 + wid;
    if (r >= n) return;
    int f2 = lane * 2;
    unsigned int v = *(const unsigned int*)&Y[(size_t)r * 128 + f2];
    float a = fmaxf((b2f_lo(v) - smu[f2]) * sinv[f2], 0.f);
    float b = fmaxf((b2f_hi(v) - smu[f2 + 1]) * sinv[f2 + 1], 0.f);
    unsigned int w0 = *(const unsigned int*)&W2[f2];
    unsigned int w1 = *(const unsigned int*)&W2[128 + f2];
    float d0 = a * b2f_lo(w0) + b * b2f_hi(w0);
    float d1 = a * b2f_lo(w1) + b * b2f_hi(w1);
    for (int o = 32; o > 0; o >>= 1) {
        d0 += __shfl_down(d0, o, 64);
        d1 += __shfl_down(d1, o, 64);
    }
    if (lane == 0) {
        float2 o2;
        o2.x = d0 + b2f(b2v[0]);
        o2.y = d1 + b2f(b2v[1]);
        *(float2*)&out[(size_t)r * 2] = o2;
    }
}

extern "C" void kernel_launch(void* const* d_in, const int* in_sizes, int n_in,
                              void* d_out, int out_size, void* d_ws, size_t ws_size,
                              hipStream_t stream) {
    const int N = in_sizes[0] / 128;
    const int E = in_sizes[1] / 2;

    const float* x = (const float*)d_in[0];
    const int* ei = (const int*)d_in[1];
    const int* srcp = ei;
    const int* dstp = ei + E;
    float* out = (float*)d_out;

    char* w = (char*)d_ws;
    auto align256 = [](size_t v) { return (v + 255) & ~(size_t)255; };
    size_t o_xcat = 0;
    size_t o_y    = align256(o_xcat + (size_t)N * 256 * 2);
    size_t o_csr  = align256(o_y + (size_t)N * 128 * 2);
    size_t o_rs   = align256(o_csr + (size_t)E * 4);
    size_t o_pos  = align256(o_rs + (size_t)(N + 1) * 4);
    size_t o_inv  = align256(o_pos + (size_t)N * 4);
    size_t o_cnt  = align256(o_inv + (size_t)N * 4);
    size_t o_stat = o_cnt + (size_t)N * 4;            // contiguous with cnt (one memset)
    size_t o_bsum = align256(o_stat + 4 * 8192 * 4);
    size_t o_boff = align256(o_bsum + 1024 * 4);
    size_t o_wbuf = align256(o_boff + 1024 * 4);

    unsigned short* xcat = (unsigned short*)(w + o_xcat);
    unsigned short* y    = (unsigned short*)(w + o_y);
    int* csr = (int*)(w + o_csr);
    int* rs  = (int*)(w + o_rs);
    int* pos = (int*)(w + o_pos);
    float* inv = (float*)(w + o_inv);
    int* cnt = (int*)(w + o_cnt);
    float* stat = (float*)(w + o_stat);
    int* bsum = (int*)(w + o_bsum);
    int* boff = (int*)(w + o_boff);
    unsigned short* wbuf = (unsigned short*)(w + o_wbuf);

    // bf16 weight views inside wbuf
    const unsigned short* Wl[3] = {wbuf + 0,      wbuf + 32768, wbuf + 65536};
    const unsigned short* Wr[3] = {wbuf + 16384,  wbuf + 49152, wbuf + 81920};
    const unsigned short* W1b   = wbuf + 98304;
    const unsigned short* bl[3] = {wbuf + 114688, wbuf + 114816, wbuf + 114944};
    const unsigned short* b1b   = wbuf + 115072;
    const unsigned short* W2b   = wbuf + 115200;
    const unsigned short* b2b   = wbuf + 115456;

    WSrc wsrc;
    wsrc.p[0] = (const float*)d_in[2];   // Wl0
    wsrc.p[1] = (const float*)d_in[4];   // Wr0
    wsrc.p[2] = (const float*)d_in[5];   // Wl1
    wsrc.p[3] = (const float*)d_in[7];   // Wr1
    wsrc.p[4] = (const float*)d_in[8];   // Wl2
    wsrc.p[5] = (const float*)d_in[10];  // Wr2
    wsrc.p[6] = (const float*)d_in[11];  // W1
    wsrc.s[0] = (const float*)d_in[3];   // bl0
    wsrc.s[1] = (const float*)d_in[6];   // bl1
    wsrc.s[2] = (const float*)d_in[9];   // bl2
    wsrc.s[3] = (const float*)d_in[12];  // b1
    wsrc.s[4] = (const float*)d_in[13];  // W2
    wsrc.s[5] = (const float*)d_in[14];  // b2

    const int NB = (N + 255) / 256;

    // zero cnt + stat (contiguous, one memset)
    hipMemsetAsync(w + o_cnt, 0, (size_t)N * 4 + 4 * 8192 * 4, stream);

    k_cvtw<<<(115458 + 255) / 256, 256, 0, stream>>>(wsrc, wbuf);
    k_count<<<(E + 255) / 256, 256, 0, stream>>>(dstp, cnt, E);
    k_bsum<<<NB, 256, 0, stream>>>(cnt, bsum, N);
    k_scanb<<<1, 512, 0, stream>>>(bsum, boff, NB);
    k_scanf<<<NB, 256, 0, stream>>>(cnt, boff, rs, pos, inv, N);
    k_fill<<<(E + 255) / 256, 256, 0, stream>>>(srcp, dstp, pos, csr, E);
    k_copyx<<<(N * 32 + 255) / 256, 256, 0, stream>>>(x, xcat, N);

    const int gemm_grid = (N + 127) / 128;
    const int agg_grid = (N + 3) / 4;
    const int bnr_grid = (N * 16 + 255) / 256;
    const float invN = 1.0f / (float)N;

    for (int i = 0; i < 3; i++) {
        k_agg<<<agg_grid, 256, 0, stream>>>(xcat, rs, csr, inv, xcat, N);
        k_gemm<<<gemm_grid, 256, 0, stream>>>(xcat, 256, 0, Wl[i], Wr[i], bl[i], y, stat + i * 8192, N, 256);
        k_bnrelu<<<bnr_grid, 256, 0, stream>>>(y, stat + i * 8192, xcat + 128, 256, N, invN);
    }
    // layer 4: x3 lives in xcat right half (lda=256, aoff=128), K=128
    k_gemm<<<gemm_grid, 256, 0, stream>>>(xcat, 256, 128, W1b, W1b, b1b, y, stat + 3 * 8192, N, 128);
    k_bnfinal<<<agg_grid, 256, 0, stream>>>(y, stat + 3 * 8192, W2b, b2b, out, N, invN);
}

// Round 4
// 454.817 us; speedup vs baseline: 1.4705x; 1.0213x over previous
//
#include <hip/hip_runtime.h>
#include <stdint.h>

typedef __bf16 v8bf __attribute__((ext_vector_type(8)));
typedef float f32x4 __attribute__((ext_vector_type(4)));

__device__ __forceinline__ float b2f(unsigned short u) {
    unsigned int x = ((unsigned int)u) << 16;
    return __builtin_bit_cast(float, x);
}
__device__ __forceinline__ float b2f_lo(unsigned int v) {
    return __builtin_bit_cast(float, v << 16);
}
__device__ __forceinline__ float b2f_hi(unsigned int v) {
    return __builtin_bit_cast(float, v & 0xffff0000u);
}
__device__ __forceinline__ unsigned short f2b(float f) {
    unsigned int x = __builtin_bit_cast(unsigned int, f);
    unsigned int r = (x + 0x7fffu + ((x >> 16) & 1u)) >> 16;  // RNE
    return (unsigned short)r;
}

__device__ __forceinline__ void load_lds16(const void* g, void* l) {
    __builtin_amdgcn_global_load_lds(
        (__attribute__((address_space(1))) void*)(const void*)g,
        (__attribute__((address_space(3))) void*)l, 16, 0, 0);
}

// ---------------- weight conversion fp32 -> bf16 packed wbuf ----------------
// wbuf layout (bf16 elements):
//   Wl0:0  Wr0:16384  Wl1:32768  Wr1:49152  Wl2:65536  Wr2:81920  W1:98304
//   bl0:114688 bl1:114816 bl2:114944 b1:115072 W2:115200 b2:115456  (total 115458)
struct WSrc { const float* p[7]; const float* s[6]; };

__global__ void k_cvtw(WSrc w, unsigned short* __restrict__ wbuf) {
    int idx = blockIdx.x * 256 + threadIdx.x;
    if (idx >= 115458) return;
    float v;
    if (idx < 114688) {
        v = w.p[idx >> 14][idx & 16383];
    } else {
        int rem = idx - 114688;
        int t, j;
        if (rem < 512)      { t = rem >> 7; j = rem & 127; }
        else if (rem < 768) { t = 4; j = rem - 512; }
        else                { t = 5; j = rem - 768; }
        v = w.s[t][j];
    }
    wbuf[idx] = f2b(v);
}

// ---------------- CSR build ----------------
__global__ void k_count(const int* __restrict__ dst, int* __restrict__ cnt, int E) {
    int i = blockIdx.x * 256 + threadIdx.x;
    if (i < E) atomicAdd(&cnt[dst[i]], 1);
}

__global__ void k_bsum(const int* __restrict__ cnt, int* __restrict__ bsum, int n) {
    __shared__ int s[256];
    int i = blockIdx.x * 256 + threadIdx.x;
    s[threadIdx.x] = (i < n) ? cnt[i] : 0;
    __syncthreads();
    for (int o = 128; o > 0; o >>= 1) {
        if (threadIdx.x < o) s[threadIdx.x] += s[threadIdx.x + o];
        __syncthreads();
    }
    if (threadIdx.x == 0) bsum[blockIdx.x] = s[0];
}

__global__ void k_scanb(const int* __restrict__ bsum, int* __restrict__ boff, int nb) {
    __shared__ int s[512];
    int t = threadIdx.x;
    int v0 = (t < nb) ? bsum[t] : 0;
    s[t] = v0;
    __syncthreads();
    for (int o = 1; o < 512; o <<= 1) {
        int v = (t >= o) ? s[t - o] : 0;
        __syncthreads();
        s[t] += v;
        __syncthreads();
    }
    if (t < nb) boff[t] = s[t] - v0;  // exclusive
}

__global__ void k_scanf(const int* __restrict__ cnt, const int* __restrict__ boff,
                        int* __restrict__ rs, int* __restrict__ pos,
                        float* __restrict__ inv, int n) {
    __shared__ int s[256];
    int t = threadIdx.x;
    int i = blockIdx.x * 256 + t;
    int c = (i < n) ? cnt[i] : 0;
    s[t] = c;
    __syncthreads();
    for (int o = 1; o < 256; o <<= 1) {
        int v = (t >= o) ? s[t - o] : 0;
        __syncthreads();
        s[t] += v;
        __syncthreads();
    }
    int start = boff[blockIdx.x] + s[t] - c;
    if (i < n) {
        rs[i] = start;
        pos[i] = start;
        inv[i] = 1.0f / (float)max(c, 1);
        if (i == n - 1) rs[n] = start + c;
    }
}

__global__ void k_fill(const int* __restrict__ src, const int* __restrict__ dst,
                       int* __restrict__ pos, int* __restrict__ csr, int E) {
    int i = blockIdx.x * 256 + threadIdx.x;
    if (i < E) {
        int p = atomicAdd(&pos[dst[i]], 1);
        csr[p] = src[i];
    }
}

// x (fp32 N x 128) -> bf16 xcat right half (stride 256)
__global__ void k_copyx(const float* __restrict__ x, unsigned short* __restrict__ xcat, int n) {
    int i = blockIdx.x * 256 + threadIdx.x;  // one float4 = 4 elems per thread
    if (i < n * 32) {
        int row = i >> 5, c4 = (i & 31) * 4;
        float4 v = *(const float4*)&x[(size_t)row * 128 + c4];
        ushort4 o;
        o.x = f2b(v.x); o.y = f2b(v.y); o.z = f2b(v.z); o.w = f2b(v.w);
        *(ushort4*)&xcat[(size_t)row * 256 + 128 + c4] = o;
    }
}

// mean-aggregate: wave per dst row; 8-way ILP over edges (predicated tail).
__global__ __launch_bounds__(256) void k_agg(const unsigned short* __restrict__ xcat,
                                             const int* __restrict__ rs, const int* __restrict__ csr,
                                             const float* __restrict__ inv_cnt,
                                             unsigned short* __restrict__ outL, int n) {
    int wid = threadIdx.x >> 6, lane = threadIdx.x & 63;
    int d = blockIdx.x * 4 + wid;
    if (d >= n) return;
    int s = rs[d], e = rs[d + 1];
    int deg = e - s;
    float ax = 0.f, ay = 0.f;
    for (int base = 0; base < deg; base += 64) {
        int cnt64 = min(64, deg - base);
        int myidx = (base + lane < deg) ? csr[s + base + lane] : 0;
        for (int b = 0; b < cnt64; b += 8) {
            int i0 = __shfl(myidx, b, 64);
            int i1 = __shfl(myidx, b + 1, 64);
            int i2 = __shfl(myidx, b + 2, 64);
            int i3 = __shfl(myidx, b + 3, 64);
            int i4 = __shfl(myidx, b + 4, 64);
            int i5 = __shfl(myidx, b + 5, 64);
            int i6 = __shfl(myidx, b + 6, 64);
            int i7 = __shfl(myidx, b + 7, 64);
            unsigned int v0 = *(const unsigned int*)&xcat[(size_t)i0 * 256 + 128 + lane * 2];
            unsigned int v1 = *(const unsigned int*)&xcat[(size_t)i1 * 256 + 128 + lane * 2];
            unsigned int v2 = *(const unsigned int*)&xcat[(size_t)i2 * 256 + 128 + lane * 2];
            unsigned int v3 = *(const unsigned int*)&xcat[(size_t)i3 * 256 + 128 + lane * 2];
            unsigned int v4 = *(const unsigned int*)&xcat[(size_t)i4 * 256 + 128 + lane * 2];
            unsigned int v5 = *(const unsigned int*)&xcat[(size_t)i5 * 256 + 128 + lane * 2];
            unsigned int v6 = *(const unsigned int*)&xcat[(size_t)i6 * 256 + 128 + lane * 2];
            unsigned int v7 = *(const unsigned int*)&xcat[(size_t)i7 * 256 + 128 + lane * 2];
            float w1 = (b + 1 < cnt64) ? 1.f : 0.f;
            float w2 = (b + 2 < cnt64) ? 1.f : 0.f;
            float w3 = (b + 3 < cnt64) ? 1.f : 0.f;
            float w4 = (b + 4 < cnt64) ? 1.f : 0.f;
            float w5 = (b + 5 < cnt64) ? 1.f : 0.f;
            float w6 = (b + 6 < cnt64) ? 1.f : 0.f;
            float w7 = (b + 7 < cnt64) ? 1.f : 0.f;
            ax += b2f_lo(v0);            ay += b2f_hi(v0);
            ax += w1 * b2f_lo(v1);       ay += w1 * b2f_hi(v1);
            ax += w2 * b2f_lo(v2);       ay += w2 * b2f_hi(v2);
            ax += w3 * b2f_lo(v3);       ay += w3 * b2f_hi(v3);
            ax += w4 * b2f_lo(v4);       ay += w4 * b2f_hi(v4);
            ax += w5 * b2f_lo(v5);       ay += w5 * b2f_hi(v5);
            ax += w6 * b2f_lo(v6);       ay += w6 * b2f_hi(v6);
            ax += w7 * b2f_lo(v7);       ay += w7 * b2f_hi(v7);
        }
    }
    float ic = inv_cnt[d];
    unsigned int o = ((unsigned int)f2b(ay * ic) << 16) | f2b(ax * ic);
    *(unsigned int*)&outL[(size_t)d * 256 + lane * 2] = o;
}

// C(nrows x 128) = A(nrows x K, lda, +aoff) @ W^T, fused column stats (32 slices).
// BK=64 (two 32-k LDS chunks), operand-swapped MFMA so each lane holds 4
// consecutive COLUMNS of one row -> packed 8-B stores (full-line writes).
__global__ __launch_bounds__(256) void k_gemm(const unsigned short* __restrict__ A, int lda, int aoff,
                                              const unsigned short* __restrict__ W0,
                                              const unsigned short* __restrict__ W1,
                                              const unsigned short* __restrict__ bias,
                                              unsigned short* __restrict__ Y,
                                              float* __restrict__ statp, int nrows, int K) {
    __shared__ __align__(16) unsigned short As[2 * 128 * 32];
    __shared__ __align__(16) unsigned short Ws[2 * 128 * 32];
    int t = threadIdx.x;
    int wid = t >> 6, lane = t & 63;
    int wm = wid >> 1, wn = wid & 1;
    int quad = lane >> 4, l16 = lane & 15;
    int m0 = blockIdx.x * 128;
    int srow = t >> 2;         // 0..63
    int scol = (t & 3) * 8;    // 0,8,16,24

    f32x4 acc[4][4] = {};  // acc[i][j]: row = m0+wm*64+i*16+l16, cols = wn*64+j*16+quad*4+r

    for (int kc = 0; kc < K; kc += 64) {
        for (int h = 0; h < 2; h++) {
            int kk = kc + h * 32;
            for (int q = 0; q < 2; q++) {
                int r = q * 64 + srow;
                int gr = m0 + r;
                if (gr >= nrows) gr = nrows - 1;
                load_lds16(A + (size_t)gr * lda + aoff + kk + scol, &As[h * 4096 + r * 32 + scol]);
            }
            const unsigned short* Wp = (kk < 128) ? W0 : W1;
            int wkc = (kk < 128) ? kk : kk - 128;
            for (int q = 0; q < 2; q++) {
                int r = q * 64 + srow;
                load_lds16(Wp + (size_t)r * 128 + wkc + scol, &Ws[h * 4096 + r * 32 + scol]);
            }
        }
        __syncthreads();
        for (int h = 0; h < 2; h++) {
            v8bf af[4], bfv[4];
            for (int i = 0; i < 4; i++)
                af[i] = *(const v8bf*)&As[h * 4096 + (wm * 64 + i * 16 + l16) * 32 + quad * 8];
            for (int j = 0; j < 4; j++)
                bfv[j] = *(const v8bf*)&Ws[h * 4096 + (wn * 64 + j * 16 + l16) * 32 + quad * 8];
            for (int i = 0; i < 4; i++)
                for (int j = 0; j < 4; j++)
                    acc[i][j] = __builtin_amdgcn_mfma_f32_16x16x32_bf16(bfv[j], af[i], acc[i][j], 0, 0, 0);
        }
        __syncthreads();
    }

    float* sp = statp + (blockIdx.x & 31) * 256;
    int row0 = m0 + wm * 64 + l16;
    for (int j = 0; j < 4; j++) {
        int c0 = wn * 64 + j * 16 + quad * 4;
        uint2 bu = *(const uint2*)&bias[c0];
        float bn0 = b2f_lo(bu.x), bn1 = b2f_hi(bu.x);
        float bn2 = b2f_lo(bu.y), bn3 = b2f_hi(bu.y);
        f32x4 cs = {0.f, 0.f, 0.f, 0.f}, cq = {0.f, 0.f, 0.f, 0.f};
        for (int i = 0; i < 4; i++) {
            int r = row0 + i * 16;
            float v0 = acc[i][j][0] + bn0;
            float v1 = acc[i][j][1] + bn1;
            float v2 = acc[i][j][2] + bn2;
            float v3 = acc[i][j][3] + bn3;
            if (r < nrows) {
                uint2 o;
                o.x = ((unsigned int)f2b(v1) << 16) | f2b(v0);
                o.y = ((unsigned int)f2b(v3) << 16) | f2b(v2);
                *(uint2*)&Y[(size_t)r * 128 + c0] = o;
                cs[0] += v0; cs[1] += v1; cs[2] += v2; cs[3] += v3;
                cq[0] += v0 * v0; cq[1] += v1 * v1; cq[2] += v2 * v2; cq[3] += v3 * v3;
            }
        }
        // reduce over the 16-lane row group (bits 0..3 of lane)
        for (int m = 1; m < 16; m <<= 1) {
            for (int r = 0; r < 4; r++) {
                cs[r] += __shfl_xor(cs[r], m, 64);
                cq[r] += __shfl_xor(cq[r], m, 64);
            }
        }
        if (l16 == 0) {
            for (int r = 0; r < 4; r++) {
                atomicAdd(&sp[c0 + r], cs[r]);
                atomicAdd(&sp[128 + c0 + r], cq[r]);
            }
        }
    }
}

// reduce 32-slice stats -> muinv[0:128]=mu, muinv[128:256]=rsqrt(var+eps)
__global__ void k_bnfin(const float* __restrict__ statp, float* __restrict__ muinv, float invN) {
    int f = threadIdx.x;  // 128
    float s = 0.f, q = 0.f;
    for (int sl = 0; sl < 32; sl++) {
        s += statp[sl * 256 + f];
        q += statp[sl * 256 + 128 + f];
    }
    float mu = s * invN;
    float var = q * invN - mu * mu;
    muinv[f] = mu;
    muinv[128 + f] = rsqrtf(var + 1e-5f);
}

// BN + ReLU + bf16 pack; uint4 (8 feats/thread)
__global__ __launch_bounds__(256) void k_bnrelu(const unsigned short* __restrict__ Y,
                                                const float* __restrict__ muinv,
                                                unsigned short* __restrict__ out, int ldo, int n) {
    __shared__ float smu[128], sinv[128];
    int t = threadIdx.x;
    if (t < 128) { smu[t] = muinv[t]; sinv[t] = muinv[128 + t]; }
    __syncthreads();
    int i = blockIdx.x * 256 + t;  // 8 feats per thread
    if (i >= n * 16) return;
    int row = i >> 4, f8 = (i & 15) * 8;
    uint4 v = *(const uint4*)&Y[(size_t)row * 128 + f8];
    unsigned int u[4] = {v.x, v.y, v.z, v.w};
    uint4 o;
    unsigned int* op = (unsigned int*)&o;
    for (int k = 0; k < 4; k++) {
        int f = f8 + k * 2;
        float a = fmaxf((b2f_lo(u[k]) - smu[f]) * sinv[f], 0.f);
        float b = fmaxf((b2f_hi(u[k]) - smu[f + 1]) * sinv[f + 1], 0.f);
        op[k] = ((unsigned int)f2b(b) << 16) | f2b(a);
    }
    *(uint4*)&out[(size_t)row * ldo + f8] = o;
}

// layer-4 BN + ReLU + final 128->2 projection fused; wave per row, fp32 out
__global__ __launch_bounds__(256) void k_bnfinal(const unsigned short* __restrict__ Y,
                                                 const float* __restrict__ muinv,
                                                 const unsigned short* __restrict__ W2,
                                                 const unsigned short* __restrict__ b2v,
                                                 float* __restrict__ out, int n) {
    __shared__ float smu[128], sinv[128];
    int t = threadIdx.x;
    if (t < 128) { smu[t] = muinv[t]; sinv[t] = muinv[128 + t]; }
    __syncthreads();
    int wid = t >> 6, lane = t & 63;
    int r = blockIdx.x * 4 + wid;
    if (r >= n) return;
    int f2 = lane * 2;
    unsigned int v = *(const unsigned int*)&Y[(size_t)r * 128 + f2];
    float a = fmaxf((b2f_lo(v) - smu[f2]) * sinv[f2], 0.f);
    float b = fmaxf((b2f_hi(v) - smu[f2 + 1]) * sinv[f2 + 1], 0.f);
    unsigned int w0 = *(const unsigned int*)&W2[f2];
    unsigned int w1 = *(const unsigned int*)&W2[128 + f2];
    float d0 = a * b2f_lo(w0) + b * b2f_hi(w0);
    float d1 = a * b2f_lo(w1) + b * b2f_hi(w1);
    for (int o = 32; o > 0; o >>= 1) {
        d0 += __shfl_down(d0, o, 64);
        d1 += __shfl_down(d1, o, 64);
    }
    if (lane == 0) {
        float2 o2;
        o2.x = d0 + b2f(b2v[0]);
        o2.y = d1 + b2f(b2v[1]);
        *(float2*)&out[(size_t)r * 2] = o2;
    }
}

extern "C" void kernel_launch(void* const* d_in, const int* in_sizes, int n_in,
                              void* d_out, int out_size, void* d_ws, size_t ws_size,
                              hipStream_t stream) {
    const int N = in_sizes[0] / 128;
    const int E = in_sizes[1] / 2;

    const float* x = (const float*)d_in[0];
    const int* ei = (const int*)d_in[1];
    const int* srcp = ei;
    const int* dstp = ei + E;
    float* out = (float*)d_out;

    char* w = (char*)d_ws;
    auto align256 = [](size_t v) { return (v + 255) & ~(size_t)255; };
    size_t o_xcat = 0;
    size_t o_y    = align256(o_xcat + (size_t)N * 256 * 2);
    size_t o_csr  = align256(o_y + (size_t)N * 128 * 2);
    size_t o_rs   = align256(o_csr + (size_t)E * 4);
    size_t o_pos  = align256(o_rs + (size_t)(N + 1) * 4);
    size_t o_inv  = align256(o_pos + (size_t)N * 4);
    size_t o_cnt  = align256(o_inv + (size_t)N * 4);
    size_t o_stat = o_cnt + (size_t)N * 4;            // contiguous with cnt (one memset)
    size_t o_muinv= align256(o_stat + 4 * 8192 * 4);
    size_t o_bsum = align256(o_muinv + 256 * 4);
    size_t o_boff = align256(o_bsum + 1024 * 4);
    size_t o_wbuf = align256(o_boff + 1024 * 4);

    unsigned short* xcat = (unsigned short*)(w + o_xcat);
    unsigned short* y    = (unsigned short*)(w + o_y);
    int* csr = (int*)(w + o_csr);
    int* rs  = (int*)(w + o_rs);
    int* pos = (int*)(w + o_pos);
    float* inv = (float*)(w + o_inv);
    int* cnt = (int*)(w + o_cnt);
    float* stat = (float*)(w + o_stat);
    float* muinv = (float*)(w + o_muinv);
    int* bsum = (int*)(w + o_bsum);
    int* boff = (int*)(w + o_boff);
    unsigned short* wbuf = (unsigned short*)(w + o_wbuf);

    // bf16 weight views inside wbuf
    const unsigned short* Wl[3] = {wbuf + 0,      wbuf + 32768, wbuf + 65536};
    const unsigned short* Wr[3] = {wbuf + 16384,  wbuf + 49152, wbuf + 81920};
    const unsigned short* W1b   = wbuf + 98304;
    const unsigned short* bl[3] = {wbuf + 114688, wbuf + 114816, wbuf + 114944};
    const unsigned short* b1b   = wbuf + 115072;
    const unsigned short* W2b   = wbuf + 115200;
    const unsigned short* b2b   = wbuf + 115456;

    WSrc wsrc;
    wsrc.p[0] = (const float*)d_in[2];   // Wl0
    wsrc.p[1] = (const float*)d_in[4];   // Wr0
    wsrc.p[2] = (const float*)d_in[5];   // Wl1
    wsrc.p[3] = (const float*)d_in[7];   // Wr1
    wsrc.p[4] = (const float*)d_in[8];   // Wl2
    wsrc.p[5] = (const float*)d_in[10];  // Wr2
    wsrc.p[6] = (const float*)d_in[11];  // W1
    wsrc.s[0] = (const float*)d_in[3];   // bl0
    wsrc.s[1] = (const float*)d_in[6];   // bl1
    wsrc.s[2] = (const float*)d_in[9];   // bl2
    wsrc.s[3] = (const float*)d_in[12];  // b1
    wsrc.s[4] = (const float*)d_in[13];  // W2
    wsrc.s[5] = (const float*)d_in[14];  // b2

    const int NB = (N + 255) / 256;

    // zero cnt + stat (contiguous, one memset)
    hipMemsetAsync(w + o_cnt, 0, (size_t)N * 4 + 4 * 8192 * 4, stream);

    k_cvtw<<<(115458 + 255) / 256, 256, 0, stream>>>(wsrc, wbuf);
    k_count<<<(E + 255) / 256, 256, 0, stream>>>(dstp, cnt, E);
    k_bsum<<<NB, 256, 0, stream>>>(cnt, bsum, N);
    k_scanb<<<1, 512, 0, stream>>>(bsum, boff, NB);
    k_scanf<<<NB, 256, 0, stream>>>(cnt, boff, rs, pos, inv, N);
    k_fill<<<(E + 255) / 256, 256, 0, stream>>>(srcp, dstp, pos, csr, E);
    k_copyx<<<(N * 32 + 255) / 256, 256, 0, stream>>>(x, xcat, N);

    const int gemm_grid = (N + 127) / 128;
    const int agg_grid = (N + 3) / 4;
    const int bnr_grid = (N * 16 + 255) / 256;
    const float invN = 1.0f / (float)N;

    for (int i = 0; i < 3; i++) {
        k_agg<<<agg_grid, 256, 0, stream>>>(xcat, rs, csr, inv, xcat, N);
        k_gemm<<<gemm_grid, 256, 0, stream>>>(xcat, 256, 0, Wl[i], Wr[i], bl[i], y, stat + i * 8192, N, 256);
        k_bnfin<<<1, 128, 0, stream>>>(stat + i * 8192, muinv, invN);
        k_bnrelu<<<bnr_grid, 256, 0, stream>>>(y, muinv, xcat + 128, 256, N);
    }
    // layer 4: x3 lives in xcat right half (lda=256, aoff=128), K=128
    k_gemm<<<gemm_grid, 256, 0, stream>>>(xcat, 256, 128, W1b, W1b, b1b, y, stat + 3 * 8192, N, 128);
    k_bnfin<<<1, 128, 0, stream>>>(stat + 3 * 8192, muinv, invN);
    k_bnfinal<<<agg_grid, 256, 0, stream>>>(y, muinv, W2b, b2b, out, N);
}